// Round 14
// baseline (606.301 us; speedup 1.0000x reference)
//
#include <hip/hip_runtime.h>

#define NN 20000
#define EE 320000
#define DD 128
#define LL 5
#define EVV 5
#define BNEPS 1e-5f
#define FB 2500             // fused agg+gemm row-blocks: NN/8 exactly
#define EMB_BLOCKS 2500     // NN*32/256
#define CVT_BLOCKS 160      // 2*5*128*128/4/256
#define CNT_BLOCKS 1250     // EE/256

typedef __attribute__((ext_vector_type(8))) short bf8_t;           // 8 bf16 (4 VGPRs)
typedef __attribute__((ext_vector_type(4))) float f4_t;            // 4 fp32
typedef __attribute__((ext_vector_type(8))) unsigned short us8;    // 16B of bf16

__device__ inline unsigned short f2bf(float f) {
    union { float f; unsigned u; } v;
    v.f = f;
    unsigned r = v.u + 0x7fffu + ((v.u >> 16) & 1u);  // RTN-even
    return (unsigned short)(r >> 16);
}
__device__ inline float bf2f(unsigned short h) {
    union { unsigned u; float f; } v;
    v.u = ((unsigned)h) << 16;
    return v.f;
}
__device__ inline float4 bf2f4(ushort4 u) {
    float4 f;
    f.x = bf2f(u.x); f.y = bf2f(u.y); f.z = bf2f(u.z); f.w = bf2f(u.w);
    return f;
}
__device__ inline float4 add4(float4 a, float4 b) {
    float4 r;
    r.x = a.x + b.x; r.y = a.y + b.y; r.z = a.z + b.z; r.w = a.w + b.w;
    return r;
}

// BN-affine + optional relu + cross-stitch for one float4 pair (both towers)
__device__ inline void xform4(float4 v1, float4 v2,
                              float4 s1, float4 t1, float4 s2, float4 t2,
                              float c00, float c01, float c10, float c11,
                              int dorelu, float4& n1, float4& n2) {
    float x1, x2, m1, m2;
#define XE(f)                                                    \
    x1 = v1.f * s1.f + t1.f;                                     \
    x2 = v2.f * s2.f + t2.f;                                     \
    x1 = dorelu ? fmaxf(x1, 0.f) : x1;                           \
    x2 = dorelu ? fmaxf(x2, 0.f) : x2;                           \
    m1 = c00 * x1 + c01 * x2;                                    \
    m2 = c10 * m1 + c11 * x2;                                    \
    n1.f = m1;                                                   \
    n2.f = m2;
    XE(x) XE(y) XE(z) XE(w)
#undef XE
}

// Per-thread BN scale/shift (channels 4c..4c+3, both towers) from raw {sum,sumsq}
__device__ inline void bn_coeffs(const float* __restrict__ statsL,
                                 const float* __restrict__ gall,
                                 const float* __restrict__ btall,
                                 int pl, int c,
                                 float4& s1, float4& t1, float4& s2, float4& t2) {
    const float inv = 1.0f / (float)NN;
    int ch = c * 4;
#define BNC(tw, sv, tv)                                                       \
    {                                                                         \
        const float* gp = gall + (size_t)((tw) * LL + pl) * DD + ch;          \
        const float* bp = btall + (size_t)((tw) * LL + pl) * DD + ch;         \
        float r[4];                                                           \
        _Pragma("unroll") for (int j = 0; j < 4; j++) {                       \
            float sum = statsL[(tw) * 256 + ch + j];                          \
            float sq = statsL[(tw) * 256 + 128 + ch + j];                     \
            float mu = sum * inv;                                             \
            float var = sq * inv - mu * mu;                                   \
            float rs = rsqrtf(var + BNEPS);                                   \
            float sc = rs * gp[j];                                            \
            r[j] = sc;                                                        \
            ((float*)&tv)[j] = bp[j] - mu * sc;                               \
        }                                                                     \
        sv.x = r[0]; sv.y = r[1]; sv.z = r[2]; sv.w = r[3];                   \
    }
    BNC(0, s1, t1)
    BNC(1, s2, t2)
#undef BNC
}

__device__ inline ushort4 hi4(float4 v) {
    ushort4 h;
    h.x = f2bf(v.x); h.y = f2bf(v.y); h.z = f2bf(v.z); h.w = f2bf(v.w);
    return h;
}
__device__ inline ushort4 lo4(float4 v, ushort4 h) {
    ushort4 l;
    l.x = f2bf(v.x - bf2f(h.x)); l.y = f2bf(v.y - bf2f(h.y));
    l.z = f2bf(v.z - bf2f(h.z)); l.w = f2bf(v.w - bf2f(h.w));
    return l;
}

// ---------------- prep: embed -> bf16 hi/lo (eh/el) + W hi/lo + etab bf16 + degree + stats zero ----------------

__global__ __launch_bounds__(256) void prep_kernel(
    const int* __restrict__ x,
    const float4* __restrict__ e1, const float4* __restrict__ e2,
    ushort4* __restrict__ eh, ushort4* __restrict__ el,
    const float4* __restrict__ Wall,
    ushort4* __restrict__ Wbh, ushort4* __restrict__ Wbl,
    const int* __restrict__ dst, int* __restrict__ deg,
    float* __restrict__ stats,
    const float* __restrict__ etab, unsigned short* __restrict__ etb2) {
    int bid = blockIdx.x;
    int tid = threadIdx.x;
    if (bid < EMB_BLOCKS) {
        int idx = bid * 256 + tid;  // < NN*32 exactly
        int r = idx >> 5, c = idx & 31;
        int v = x[r];
        float4 w1 = e1[v * 32 + c];
        float4 w2 = e2[v * 32 + c];
        ushort4 h = hi4(w1);
        eh[(size_t)r * 64 + c] = h;
        el[(size_t)r * 64 + c] = lo4(w1, h);
        h = hi4(w2);
        eh[(size_t)r * 64 + 32 + c] = h;
        el[(size_t)r * 64 + 32 + c] = lo4(w2, h);
    } else if (bid < EMB_BLOCKS + CVT_BLOCKS) {
        int i = (bid - EMB_BLOCKS) * 256 + tid;
        float4 w = Wall[i];
        ushort4 oh = hi4(w);
        Wbh[i] = oh;
        Wbl[i] = lo4(w, oh);
    } else if (bid < EMB_BLOCKS + CVT_BLOCKS + CNT_BLOCKS) {
        int e = (bid - EMB_BLOCKS - CVT_BLOCKS) * 256 + tid;  // < EE exactly
        atomicAdd(&deg[dst[e]], 1);
    } else {
        // zero all layers' raw BN-stat accumulators: 5 * 512 floats
#pragma unroll
        for (int i = 0; i < 10; i++) stats[i * 256 + tid] = 0.f;
        // etab -> bf16, interleaved layout (l, attr, tower, ch): matches h' row layout
        for (int idx = tid; idx < 2 * LL * EVV * DD; idx += 256) {
            int ch = idx & 127;
            int tw = (idx >> 7) & 1;
            int la = idx >> 8;
            int a = la % EVV;
            int l = la / EVV;
            etb2[idx] = f2bf(etab[((size_t)(tw * LL + l) * EVV + a) * DD + ch]);
        }
    }
}

// ---------------- CSR scan (wave-shuffle based) ----------------

__global__ __launch_bounds__(1024) void scan_kernel(const int* __restrict__ deg,
                                                    int* __restrict__ offs,
                                                    int* __restrict__ pos) {
    __shared__ int wsum[16];
    int t = threadIdx.x;
    int lane = t & 63, wv = t >> 6;
    int base = t * 20;
    int loc[20];
    int s = 0;
#pragma unroll
    for (int i = 0; i < 20; i++) {
        int j = base + i;
        int d = (j < NN) ? deg[j] : 0;
        loc[i] = d;
        s += d;
    }
    int incl = s;
#pragma unroll
    for (int o = 1; o < 64; o <<= 1) {
        int v = __shfl_up(incl, o, 64);
        if (lane >= o) incl += v;
    }
    if (lane == 63) wsum[wv] = incl;
    __syncthreads();
    if (t < 16) {
        int v = wsum[t];
        int iv = v;
#pragma unroll
        for (int o = 1; o < 16; o <<= 1) {
            int u = __shfl_up(iv, o, 64);
            if (t >= o) iv += u;
        }
        wsum[t] = iv - v;  // exclusive wave offset
    }
    __syncthreads();
    int run = wsum[wv] + (incl - s);
#pragma unroll
    for (int i = 0; i < 20; i++) {
        int j = base + i;
        if (j < NN) {
            offs[j] = run;
            pos[j] = run;
            run += loc[i];
        }
    }
}

__global__ __launch_bounds__(256) void scatter_kernel(const int* __restrict__ src,
                                                      const int* __restrict__ dst,
                                                      const int* __restrict__ eattr,
                                                      int* __restrict__ pos,
                                                      int2* __restrict__ erec) {
    int e = blockIdx.x * 256 + threadIdx.x;
    if (e < EE) {
        int d = dst[e];
        int p = atomicAdd(&pos[d], 1);
        erec[p] = make_int2(src[e], eattr[e]);
    }
}

// ---------------- xform: y(hi+lo) -> BN+relu+cross -> h' (hi/lo planes), once per node ----------------

__global__ __launch_bounds__(256) void xform_kernel(
    const ushort4* __restrict__ yh, const ushort4* __restrict__ yl,
    ushort4* __restrict__ hph, ushort4* __restrict__ hpl,
    const float* __restrict__ statsL,
    const float* __restrict__ gall, const float* __restrict__ btall,
    const float* __restrict__ crossp, int pl) {
    int idx = blockIdx.x * 256 + threadIdx.x;  // < NN*32 exactly
    int r = idx >> 5, c = idx & 31;
    float4 s1, t1, s2, t2;
    bn_coeffs(statsL, gall, btall, pl, c, s1, t1, s2, t2);
    float c00 = crossp[0], c01 = crossp[1], c10 = crossp[2], c11 = crossp[3];
    float4 v1 = add4(bf2f4(yh[(size_t)r * 64 + c]), bf2f4(yl[(size_t)r * 64 + c]));
    float4 v2 = add4(bf2f4(yh[(size_t)r * 64 + 32 + c]), bf2f4(yl[(size_t)r * 64 + 32 + c]));
    float4 n1, n2;
    xform4(v1, v2, s1, t1, s2, t2, c00, c01, c10, c11, 1, n1, n2);
    ushort4 h = hi4(n1);
    hph[(size_t)r * 64 + c] = h;
    hpl[(size_t)r * 64 + c] = lo4(n1, h);
    h = hi4(n2);
    hph[(size_t)r * 64 + 32 + c] = h;
    hpl[(size_t)r * 64 + 32 + c] = lo4(n2, h);
}

// ---------------- fused aggregate + MFMA GEMM (wave-per-row, 8-row blocks) ----------------
// Round-13 geometry change ONLY: block = 8 node-rows x both towers, 512 threads = 8 waves,
//   grid 2500 (NN/8 exactly). Phase A is character-identical to the round-9 body
//   (wave-per-row, slot = lane>>5, c = lane&31, 8 edges/iter + 2-wide predicated
//   remainder, shfl_xor(32) reduce) -> u bitwise identical. Rationale: the Phase-A/B
//   __syncthreads gates the block on its slowest row's degree; max-of-8 < max-of-16,
//   and 2500 blocks (4/CU co-res, 32 waves/CU) smooth the dispatch tail.
// Phase B: uS padded to 16 rows (rows 8-15 zeroed; zero rows are swizzle-invariant);
//   each wave computes TWO 16x16 column-tiles (tiles 2w, 2w+1; 24 MFMAs — MFMA util
//   is ~2%, extra zero-row MFMA work is irrelevant). Stats/stores guarded to rows < 8.
// SPILL GUARD (rounds 11/12): do not add long-lived state to Phase A. Guard metrics:
//   WRITE_SIZE ~22.5MB, FETCH ~67MB, VGPR ~40.
// RACE NOTE: gather source (hph/hpl, or eh/el at l=0) is DISJOINT from GEMM dest yh/yl.
// LDS: uS 16x64 us8 = 16KB (4096 floats, epilogue accS 8x8x33=2112 floats aliases it)
//   + sP 2KB = ~18KB. __launch_bounds__(512,8): VGPR<=64 (round-6 config measured 40).

__global__ __launch_bounds__(512, 8) void agg_gemm_kernel(
    const us8* __restrict__ hph, const us8* __restrict__ hpl,
    const us8* __restrict__ etb2, int layer,
    const int* __restrict__ offs, const int* __restrict__ deg,
    const int2* __restrict__ erec, const float* __restrict__ epsall,
    const unsigned short* __restrict__ Wbh, const unsigned short* __restrict__ Wbl,
    const float* __restrict__ ball,
    unsigned short* __restrict__ yh, unsigned short* __restrict__ yl,
    float* __restrict__ statsL) {
    __shared__ float accS[4096];            // 16KB: uS 16x64 us8; epilogue accS aliases
    __shared__ float sP[2][2][DD];          // [tower][{sum,sq}][ch]
    us8* uS = (us8*)accS;                   // [row][unit ^ (row&7)] 16 x 64 us8

    int tid = threadIdx.x;
    int w = tid >> 6, lane = tid & 63;

    // zero-pad uS rows 8..15 (one us8 per thread: 8 rows x 64 units = 512)
    {
        us8 z;
#pragma unroll
        for (int k = 0; k < 8; k++) z[k] = 0;
        uS[(8 + (tid >> 6)) * 64 + (tid & 63)] = z;
    }

    // ---- Phase A: aggregate — wave w handles row w (one node, both towers) ----
    {
        int row = w;
        int node = blockIdx.x * 8 + row;    // < NN exactly (2500*8 == NN)
        int slot = lane >> 5;               // 2 edge slots
        int c = lane & 31;                  // us8 unit: 0..15 t0, 16..31 t1
        const us8* et = etb2 + (size_t)layer * EVV * 32;
        float ep = 1.0f + epsall[(c >> 4) * LL + layer];

        int off = offs[node];
        int dg = deg[node];
        float a[8];
#pragma unroll
        for (int k = 0; k < 8; k++) a[k] = 0.f;
        int i = 0;
        // main: 8 edges per iter (4 per slot); 16B/lane gathers
        for (; i + 8 <= dg; i += 8) {
            int2 r0 = erec[off + i + slot];
            int2 r1 = erec[off + i + 2 + slot];
            int2 r2 = erec[off + i + 4 + slot];
            int2 r3 = erec[off + i + 6 + slot];
            us8 h0 = hph[(size_t)r0.x * 32 + c];
            us8 h1 = hph[(size_t)r1.x * 32 + c];
            us8 h2 = hph[(size_t)r2.x * 32 + c];
            us8 h3 = hph[(size_t)r3.x * 32 + c];
            us8 e0 = et[r0.y * 32 + c];
            us8 e1 = et[r1.y * 32 + c];
            us8 e2 = et[r2.y * 32 + c];
            us8 e3 = et[r3.y * 32 + c];
#pragma unroll
            for (int k = 0; k < 8; k++) {
                a[k] += fmaxf(bf2f(h0[k]) + bf2f(e0[k]), 0.f);
                a[k] += fmaxf(bf2f(h1[k]) + bf2f(e1[k]), 0.f);
                a[k] += fmaxf(bf2f(h2[k]) + bf2f(e2[k]), 0.f);
                a[k] += fmaxf(bf2f(h3[k]) + bf2f(e3[k]), 0.f);
            }
        }
        // remainder (<=7), 2 edges per iter, predicated
        for (; i < dg; i += 2) {
            int j = i + slot;
            bool valid = j < dg;
            int e = off + (valid ? j : 0);
            int2 r = erec[e];
            us8 h = hph[(size_t)r.x * 32 + c];
            us8 ev = et[r.y * 32 + c];
            if (valid) {
#pragma unroll
                for (int k = 0; k < 8; k++) a[k] += fmaxf(bf2f(h[k]) + bf2f(ev[k]), 0.f);
            }
        }
        // reduce across the 2 slots
#pragma unroll
        for (int k = 0; k < 8; k++) a[k] += __shfl_xor(a[k], 32, 64);

        // self (exact hi+lo): u = (1+eps)*h' + agg; split hi/lo
        us8 sh = hph[(size_t)node * 32 + c];
        us8 sl = hpl[(size_t)node * 32 + c];
        us8 uh, ul;
#pragma unroll
        for (int k = 0; k < 8; k++) {
            float u = ep * (bf2f(sh[k]) + bf2f(sl[k])) + a[k];
            unsigned short h = f2bf(u);
            uh[k] = h;
            ul[k] = f2bf(u - bf2f(h));
        }
        // u row = 64 us8: [t0hi 16][t1hi 16][t0lo 16][t1lo 16]; slot0 -> hi, slot1 -> lo
        int unit = slot * 32 + c;
        uS[row * 64 + (unit ^ (row & 7))] = slot ? ul : uh;
    }
    __syncthreads();

    // ---- Phase B: GEMM (8 valid rows x 256 cols; 8 waves x 2 tiles) ----
    int quad = lane >> 4, m = lane & 15;
    const bf8_t* u8 = (const bf8_t*)uS;
    int lrow = m;           // A-row = lane m (rows 8-15 are zero padding)
    int sw = lrow & 7;

    f4_t accv[2];
    int twt[2], ntt[2];
#pragma unroll
    for (int tt = 0; tt < 2; tt++) {
        int tile = w * 2 + tt;              // 0..15
        int tw = tile >> 3, nt = tile & 7;
        twt[tt] = tw; ntt[tt] = nt;
        const bf8_t* Wh8 = (const bf8_t*)(Wbh + (size_t)(tw * LL + layer) * DD * DD);
        const bf8_t* Wl8 = (const bf8_t*)(Wbl + (size_t)(tw * LL + layer) * DD * DD);
        f4_t acc;
        acc[0] = 0.f; acc[1] = 0.f; acc[2] = 0.f; acc[3] = 0.f;
#pragma unroll
        for (int kt = 0; kt < 4; kt++) {
            int x = kt * 4 + quad;
            bf8_t ah = u8[lrow * 64 + (tw * 16 + (x ^ sw))];
            bf8_t al = u8[lrow * 64 + (32 + tw * 16 + (x ^ sw))];
            bf8_t bh = Wh8[(nt * 16 + m) * 16 + x];
            bf8_t bl = Wl8[(nt * 16 + m) * 16 + x];
            acc = __builtin_amdgcn_mfma_f32_16x16x32_bf16(ah, bh, acc, 0, 0, 0);
            acc = __builtin_amdgcn_mfma_f32_16x16x32_bf16(al, bh, acc, 0, 0, 0);
            acc = __builtin_amdgcn_mfma_f32_16x16x32_bf16(ah, bl, acc, 0, 0, 0);
        }
        accv[tt] = acc;
    }
    __syncthreads();  // uS dead; accS about to be written

    // Epilogue: per tile, D col = nt*16 + m, row = quad*4 + r (valid rows < 8 only).
#pragma unroll
    for (int tt = 0; tt < 2; tt++) {
        int tw = twt[tt], nt = ntt[tt];
        const float* bias = ball + (size_t)(tw * LL + layer) * DD;
        int col = nt * 16 + m;
        float bv = bias[col];
        int gc = tw * 128 + col;
        int cg = gc >> 5, kk = gc & 31;
        float s = 0.f, q = 0.f;
#pragma unroll
        for (int r = 0; r < 4; r++) {
            int lr2 = quad * 4 + r;
            if (lr2 < 8) {
                float v = accv[tt][r] + bv;
                accS[(lr2 * 8 + cg) * 33 + kk] = v;
                s += v; q += v * v;
            }
        }
        s += __shfl_xor(s, 16, 64); s += __shfl_xor(s, 32, 64);
        q += __shfl_xor(q, 16, 64); q += __shfl_xor(q, 32, 64);
        if (quad == 0) {
            sP[tw][0][col] = s;
            sP[tw][1][col] = q;
        }
    }
    __syncthreads();

    // vectorized hi/lo stores: t<256 -> yh, t>=256 -> yl; row = (t&255)>>5, unit = t&31
    {
        int t = tid & 255;
        int row = t >> 5, unit = t & 31;   // unit: us8 of the 512B y-row
        int grow = blockIdx.x * 8 + row;
        int cg = unit >> 2, kb = (unit & 3) * 8;
        const float* srcp = accS + (row * 8 + cg) * 33 + kb;
        us8 v8;
        if (tid < 256) {
#pragma unroll
            for (int k = 0; k < 8; k++) v8[k] = f2bf(srcp[k]);
            ((us8*)yh)[(size_t)grow * 32 + unit] = v8;
        } else {
#pragma unroll
            for (int k = 0; k < 8; k++) {
                float v = srcp[k];
                v8[k] = f2bf(v - bf2f(f2bf(v)));
            }
            ((us8*)yl)[(size_t)grow * 32 + unit] = v8;
        }
    }

    // stats: all 512 threads: tid = tw*256 + sq*128 + ch; one atomicAdd/thread
    {
        int twi = tid >> 8, idx = tid & 255;
        int sq = idx >> 7, ch = idx & 127;
        atomicAdd(&statsL[twi * 256 + idx], sP[twi][sq][ch]);
    }
}

// ---------------- final epilogue: BN (raw stats) + cross (no relu) from hi+lo -> d_out ----------------

__global__ __launch_bounds__(256) void bn_final_kernel(
    const ushort4* __restrict__ yh, const ushort4* __restrict__ yl,
    float4* __restrict__ o1, float4* __restrict__ o2,
    const float* __restrict__ statsL,
    const float* __restrict__ gall, const float* __restrict__ btall,
    const float* __restrict__ crossp) {
    int idx = blockIdx.x * 256 + threadIdx.x;  // < NN*32 exactly
    int r = idx >> 5, c = idx & 31;
    float4 s1, t1, s2, t2;
    bn_coeffs(statsL, gall, btall, LL - 1, c, s1, t1, s2, t2);
    float c00 = crossp[0], c01 = crossp[1], c10 = crossp[2], c11 = crossp[3];
    float4 v1 = add4(bf2f4(yh[(size_t)r * 64 + c]), bf2f4(yl[(size_t)r * 64 + c]));
    float4 v2 = add4(bf2f4(yh[(size_t)r * 64 + 32 + c]), bf2f4(yl[(size_t)r * 64 + 32 + c]));
    float4 n1, n2;
    xform4(v1, v2, s1, t1, s2, t2, c00, c01, c10, c11, 0, n1, n2);
    o1[(size_t)r * 32 + c] = n1;
    o2[(size_t)r * 32 + c] = n2;
}

// ---------------- launcher ----------------

extern "C" void kernel_launch(void* const* d_in, const int* in_sizes, int n_in,
                              void* d_out, int out_size, void* d_ws, size_t ws_size,
                              hipStream_t stream) {
    const int* x = (const int*)d_in[0];
    const int* eidx = (const int*)d_in[1];
    const int* eattr = (const int*)d_in[2];
    const float* emb1 = (const float*)d_in[3];
    const float* emb2 = (const float*)d_in[4];
    const float* etab = (const float*)d_in[5];
    const float* epsv = (const float*)d_in[6];
    const float* Wall = (const float*)d_in[7];
    const float* ball = (const float*)d_in[8];
    const float* gall = (const float*)d_in[9];
    const float* btall = (const float*)d_in[10];
    const float* cross = (const float*)d_in[11];
    float* out = (float*)d_out;

    const size_t ND = (size_t)NN * DD;  // 2,560,000
    char* p = (char*)d_ws;
    unsigned short* yh = (unsigned short*)p;   p += (size_t)NN * 256 * 2;  // gemm-out bf16 hi plane
    unsigned short* yl = (unsigned short*)p;   p += (size_t)NN * 256 * 2;  // gemm-out bf16 lo plane
    unsigned short* hph = (unsigned short*)p;  p += (size_t)NN * 256 * 2;  // h' hi plane
    unsigned short* hpl = (unsigned short*)p;  p += (size_t)NN * 256 * 2;  // h' lo plane
    unsigned short* eh = (unsigned short*)p;   p += (size_t)NN * 256 * 2;  // embedding hi plane
    unsigned short* el = (unsigned short*)p;   p += (size_t)NN * 256 * 2;  // embedding lo plane
    unsigned short* Wbh = (unsigned short*)p;  p += (size_t)2 * LL * DD * DD * 2;
    unsigned short* Wbl = (unsigned short*)p;  p += (size_t)2 * LL * DD * DD * 2;
    unsigned short* etb2 = (unsigned short*)p; p += (size_t)2 * LL * EVV * DD * 2;
    int* deg = (int*)p;               p += (size_t)NN * 4;
    int* offs = (int*)p;              p += (size_t)NN * 4;
    int* pos = (int*)p;               p += (size_t)NN * 4;
    int2* erec = (int2*)p;            p += (size_t)EE * 8;
    float* stats = (float*)p;         p += (size_t)LL * 512 * 4;  // per-layer raw {sum,sq}

    const int* src = eidx;
    const int* dst = eidx + EE;

    hipMemsetAsync(deg, 0, (size_t)NN * 4, stream);
    prep_kernel<<<EMB_BLOCKS + CVT_BLOCKS + CNT_BLOCKS + 1, 256, 0, stream>>>(
        x, (const float4*)emb1, (const float4*)emb2,
        (ushort4*)eh, (ushort4*)el,
        (const float4*)Wall, (ushort4*)Wbh, (ushort4*)Wbl, dst, deg, stats,
        etab, etb2);
    scan_kernel<<<1, 1024, 0, stream>>>(deg, offs, pos);
    scatter_kernel<<<EE / 256, 256, 0, stream>>>(src, dst, eattr, pos, erec);

    for (int l = 0; l < LL; l++) {
        const unsigned short* hsrc_h = eh;
        const unsigned short* hsrc_l = el;
        if (l > 0) {
            xform_kernel<<<(NN * 32) / 256, 256, 0, stream>>>(
                (const ushort4*)yh, (const ushort4*)yl,
                (ushort4*)hph, (ushort4*)hpl,
                stats + (size_t)(l - 1) * 512, gall, btall,
                cross + (l - 1) * 4, l - 1);
            hsrc_h = hph;
            hsrc_l = hpl;
        }
        agg_gemm_kernel<<<FB, 512, 0, stream>>>(
            (const us8*)hsrc_h, (const us8*)hsrc_l, (const us8*)etb2, l,
            offs, deg, erec, epsv, Wbh, Wbl, ball, yh, yl,
            stats + (size_t)l * 512);
    }
    bn_final_kernel<<<(NN * 32) / 256, 256, 0, stream>>>(
        (const ushort4*)yh, (const ushort4*)yl, (float4*)out, (float4*)(out + ND),
        stats + (size_t)(LL - 1) * 512, gall, btall, cross + (LL - 1) * 4);
}

// Round 15
// 470.860 us; speedup vs baseline: 1.2876x; 1.2876x over previous
//
#include <hip/hip_runtime.h>

#define NN 20000
#define EE 320000
#define DD 128
#define LL 5
#define EVV 5
#define BNEPS 1e-5f
#define FB 1250             // fused agg+gemm row-blocks: NN/16 exactly
#define EMB_BLOCKS 2500     // NN*32/256
#define CVT_BLOCKS 160      // 2*5*128*128/4/256
#define CNT_BLOCKS 1250     // EE/256

typedef __attribute__((ext_vector_type(8))) short bf8_t;           // 8 bf16 (4 VGPRs)
typedef __attribute__((ext_vector_type(4))) float f4_t;            // 4 fp32
typedef __attribute__((ext_vector_type(8))) unsigned short us8;    // 16B of bf16

__device__ inline unsigned short f2bf(float f) {
    union { float f; unsigned u; } v;
    v.f = f;
    unsigned r = v.u + 0x7fffu + ((v.u >> 16) & 1u);  // RTN-even
    return (unsigned short)(r >> 16);
}
__device__ inline float bf2f(unsigned short h) {
    union { unsigned u; float f; } v;
    v.u = ((unsigned)h) << 16;
    return v.f;
}
__device__ inline float4 bf2f4(ushort4 u) {
    float4 f;
    f.x = bf2f(u.x); f.y = bf2f(u.y); f.z = bf2f(u.z); f.w = bf2f(u.w);
    return f;
}
__device__ inline float4 add4(float4 a, float4 b) {
    float4 r;
    r.x = a.x + b.x; r.y = a.y + b.y; r.z = a.z + b.z; r.w = a.w + b.w;
    return r;
}

// BN-affine + optional relu + cross-stitch for one float4 pair (both towers)
__device__ inline void xform4(float4 v1, float4 v2,
                              float4 s1, float4 t1, float4 s2, float4 t2,
                              float c00, float c01, float c10, float c11,
                              int dorelu, float4& n1, float4& n2) {
    float x1, x2, m1, m2;
#define XE(f)                                                    \
    x1 = v1.f * s1.f + t1.f;                                     \
    x2 = v2.f * s2.f + t2.f;                                     \
    x1 = dorelu ? fmaxf(x1, 0.f) : x1;                           \
    x2 = dorelu ? fmaxf(x2, 0.f) : x2;                           \
    m1 = c00 * x1 + c01 * x2;                                    \
    m2 = c10 * m1 + c11 * x2;                                    \
    n1.f = m1;                                                   \
    n2.f = m2;
    XE(x) XE(y) XE(z) XE(w)
#undef XE
}

// Per-thread BN scale/shift (channels 4c..4c+3, both towers) from raw {sum,sumsq}
__device__ inline void bn_coeffs(const float* __restrict__ statsL,
                                 const float* __restrict__ gall,
                                 const float* __restrict__ btall,
                                 int pl, int c,
                                 float4& s1, float4& t1, float4& s2, float4& t2) {
    const float inv = 1.0f / (float)NN;
    int ch = c * 4;
#define BNC(tw, sv, tv)                                                       \
    {                                                                         \
        const float* gp = gall + (size_t)((tw) * LL + pl) * DD + ch;          \
        const float* bp = btall + (size_t)((tw) * LL + pl) * DD + ch;         \
        float r[4];                                                           \
        _Pragma("unroll") for (int j = 0; j < 4; j++) {                       \
            float sum = statsL[(tw) * 256 + ch + j];                          \
            float sq = statsL[(tw) * 256 + 128 + ch + j];                     \
            float mu = sum * inv;                                             \
            float var = sq * inv - mu * mu;                                   \
            float rs = rsqrtf(var + BNEPS);                                   \
            float sc = rs * gp[j];                                            \
            r[j] = sc;                                                        \
            ((float*)&tv)[j] = bp[j] - mu * sc;                               \
        }                                                                     \
        sv.x = r[0]; sv.y = r[1]; sv.z = r[2]; sv.w = r[3];                   \
    }
    BNC(0, s1, t1)
    BNC(1, s2, t2)
#undef BNC
}

__device__ inline ushort4 hi4(float4 v) {
    ushort4 h;
    h.x = f2bf(v.x); h.y = f2bf(v.y); h.z = f2bf(v.z); h.w = f2bf(v.w);
    return h;
}
__device__ inline ushort4 lo4(float4 v, ushort4 h) {
    ushort4 l;
    l.x = f2bf(v.x - bf2f(h.x)); l.y = f2bf(v.y - bf2f(h.y));
    l.z = f2bf(v.z - bf2f(h.z)); l.w = f2bf(v.w - bf2f(h.w));
    return l;
}

// ---------------- prep: embed -> bf16 hi/lo (eh/el) + W hi/lo + etab bf16 + degree + stats zero ----------------

__global__ __launch_bounds__(256) void prep_kernel(
    const int* __restrict__ x,
    const float4* __restrict__ e1, const float4* __restrict__ e2,
    ushort4* __restrict__ eh, ushort4* __restrict__ el,
    const float4* __restrict__ Wall,
    ushort4* __restrict__ Wbh, ushort4* __restrict__ Wbl,
    const int* __restrict__ dst, int* __restrict__ deg,
    float* __restrict__ stats,
    const float* __restrict__ etab, unsigned short* __restrict__ etb2) {
    int bid = blockIdx.x;
    int tid = threadIdx.x;
    if (bid < EMB_BLOCKS) {
        int idx = bid * 256 + tid;  // < NN*32 exactly
        int r = idx >> 5, c = idx & 31;
        int v = x[r];
        float4 w1 = e1[v * 32 + c];
        float4 w2 = e2[v * 32 + c];
        ushort4 h = hi4(w1);
        eh[(size_t)r * 64 + c] = h;
        el[(size_t)r * 64 + c] = lo4(w1, h);
        h = hi4(w2);
        eh[(size_t)r * 64 + 32 + c] = h;
        el[(size_t)r * 64 + 32 + c] = lo4(w2, h);
    } else if (bid < EMB_BLOCKS + CVT_BLOCKS) {
        int i = (bid - EMB_BLOCKS) * 256 + tid;
        float4 w = Wall[i];
        ushort4 oh = hi4(w);
        Wbh[i] = oh;
        Wbl[i] = lo4(w, oh);
    } else if (bid < EMB_BLOCKS + CVT_BLOCKS + CNT_BLOCKS) {
        int e = (bid - EMB_BLOCKS - CVT_BLOCKS) * 256 + tid;  // < EE exactly
        atomicAdd(&deg[dst[e]], 1);
    } else {
        // zero all layers' raw BN-stat accumulators: 5 * 512 floats
#pragma unroll
        for (int i = 0; i < 10; i++) stats[i * 256 + tid] = 0.f;
        // etab -> bf16, interleaved layout (l, attr, tower, ch): matches h' row layout
        for (int idx = tid; idx < 2 * LL * EVV * DD; idx += 256) {
            int ch = idx & 127;
            int tw = (idx >> 7) & 1;
            int la = idx >> 8;
            int a = la % EVV;
            int l = la / EVV;
            etb2[idx] = f2bf(etab[((size_t)(tw * LL + l) * EVV + a) * DD + ch]);
        }
    }
}

// ---------------- CSR scan (wave-shuffle based) ----------------

__global__ __launch_bounds__(1024) void scan_kernel(const int* __restrict__ deg,
                                                    int* __restrict__ offs,
                                                    int* __restrict__ pos) {
    __shared__ int wsum[16];
    int t = threadIdx.x;
    int lane = t & 63, wv = t >> 6;
    int base = t * 20;
    int loc[20];
    int s = 0;
#pragma unroll
    for (int i = 0; i < 20; i++) {
        int j = base + i;
        int d = (j < NN) ? deg[j] : 0;
        loc[i] = d;
        s += d;
    }
    int incl = s;
#pragma unroll
    for (int o = 1; o < 64; o <<= 1) {
        int v = __shfl_up(incl, o, 64);
        if (lane >= o) incl += v;
    }
    if (lane == 63) wsum[wv] = incl;
    __syncthreads();
    if (t < 16) {
        int v = wsum[t];
        int iv = v;
#pragma unroll
        for (int o = 1; o < 16; o <<= 1) {
            int u = __shfl_up(iv, o, 64);
            if (t >= o) iv += u;
        }
        wsum[t] = iv - v;  // exclusive wave offset
    }
    __syncthreads();
    int run = wsum[wv] + (incl - s);
#pragma unroll
    for (int i = 0; i < 20; i++) {
        int j = base + i;
        if (j < NN) {
            offs[j] = run;
            pos[j] = run;
            run += loc[i];
        }
    }
}

__global__ __launch_bounds__(256) void scatter_kernel(const int* __restrict__ src,
                                                      const int* __restrict__ dst,
                                                      const int* __restrict__ eattr,
                                                      int* __restrict__ pos,
                                                      int2* __restrict__ erec) {
    int e = blockIdx.x * 256 + threadIdx.x;
    if (e < EE) {
        int d = dst[e];
        int p = atomicAdd(&pos[d], 1);
        erec[p] = make_int2(src[e], eattr[e]);
    }
}

// ---------------- xform: y(hi+lo) -> BN+relu+cross -> h' (hi/lo planes), once per node ----------------

__global__ __launch_bounds__(256) void xform_kernel(
    const ushort4* __restrict__ yh, const ushort4* __restrict__ yl,
    ushort4* __restrict__ hph, ushort4* __restrict__ hpl,
    const float* __restrict__ statsL,
    const float* __restrict__ gall, const float* __restrict__ btall,
    const float* __restrict__ crossp, int pl) {
    int idx = blockIdx.x * 256 + threadIdx.x;  // < NN*32 exactly
    int r = idx >> 5, c = idx & 31;
    float4 s1, t1, s2, t2;
    bn_coeffs(statsL, gall, btall, pl, c, s1, t1, s2, t2);
    float c00 = crossp[0], c01 = crossp[1], c10 = crossp[2], c11 = crossp[3];
    float4 v1 = add4(bf2f4(yh[(size_t)r * 64 + c]), bf2f4(yl[(size_t)r * 64 + c]));
    float4 v2 = add4(bf2f4(yh[(size_t)r * 64 + 32 + c]), bf2f4(yl[(size_t)r * 64 + 32 + c]));
    float4 n1, n2;
    xform4(v1, v2, s1, t1, s2, t2, c00, c01, c10, c11, 1, n1, n2);
    ushort4 h = hi4(n1);
    hph[(size_t)r * 64 + c] = h;
    hpl[(size_t)r * 64 + c] = lo4(n1, h);
    h = hi4(n2);
    hph[(size_t)r * 64 + 32 + c] = h;
    hpl[(size_t)r * 64 + 32 + c] = lo4(n2, h);
}

// ---------------- fused aggregate + MFMA GEMM (wave-per-row, both towers) ----------------
// ROUND-9/13 KERNEL-OF-RECORD (verified best: 471.6/471.9us, agg ~62us @ 70% occ).
// Grid 1250: block = 16 node-rows x BOTH towers. 1024 threads = 16 waves; wave w owns
//   row w (node = blockIdx.x*16 + w) — ONE row per wave, no serial row loop. Lane map:
//   slot = lane>>5 (2 edge slots), c = lane&31 (us8 units covering both towers);
//   8 edges/iter, predicated 2/iter remainder, shfl_xor(32) slot reduce.
//   Each edge's full 512B row gathered ONCE.
// DESIGN-SPACE LEDGER (all counter-diagnosed regressions — do not retry):
//   - more rows/wave (serial chains, r3-r5), tower-split (2x traffic, r7),
//   - widened 8-wide remainder (+5MB FETCH, r10), erec-in-reg / xform-fold
//     (scratch spill at the 32-VGPR budget: WRITE balloons 22.5->67..184MB, r11/r12),
//   - 8-row blocks (2x per-row overhead + zero-row MFMAs, r14: 86.6us).
// SPILL GUARD: ANY added long-lived state in Phase A spills; watch WRITE_SIZE ~22.5MB.
// u = (1+eps)*h' + agg, split hi/lo into LDS uS[16][64] us8 (16KB), unit swizzled
//   with ^(row&7) so Phase B ds_read_b128 spreads banks.
// Phase B: wave w -> (tw = w>>3, nt = w&7): 16x16 output tile over all 16 rows;
//   12 MFMAs (4 kt x {ah*bh, al*bh, ah*bl}); epilogue math identical to verified gemm.
// RACE NOTE: gather source (hph/hpl, or eh/el at l=0) is DISJOINT from GEMM dest yh/yl.
// LDS: accS 16x8x33 fp32 = 16.9KB (first 16KB doubles as uS) + sP 2KB = ~19KB.
// __launch_bounds__(1024,8): 2 blocks/CU -> 32 waves/CU ceiling; measured VGPR 32.

__global__ __launch_bounds__(1024, 8) void agg_gemm_kernel(
    const us8* __restrict__ hph, const us8* __restrict__ hpl,
    const us8* __restrict__ etb2, int layer,
    const int* __restrict__ offs, const int* __restrict__ deg,
    const int2* __restrict__ erec, const float* __restrict__ epsall,
    const unsigned short* __restrict__ Wbh, const unsigned short* __restrict__ Wbl,
    const float* __restrict__ ball,
    unsigned short* __restrict__ yh, unsigned short* __restrict__ yl,
    float* __restrict__ statsL) {
    __shared__ float accS[16 * 8 * 33];     // 4224 floats (16.9KB); first 16KB doubles as uS
    __shared__ float sP[2][2][DD];          // [tower][{sum,sq}][ch]
    us8* uS = (us8*)accS;                   // [row][unit ^ (row&7)] 16 x 64 us8

    int tid = threadIdx.x;
    int w = tid >> 6, lane = tid & 63;

    // ---- Phase A: aggregate — wave w handles row w (one node, both towers) ----
    {
        int row = w;
        int node = blockIdx.x * 16 + row;   // < NN exactly (1250*16 == NN)
        int slot = lane >> 5;               // 2 edge slots
        int c = lane & 31;                  // us8 unit: 0..15 t0, 16..31 t1
        const us8* et = etb2 + (size_t)layer * EVV * 32;
        float ep = 1.0f + epsall[(c >> 4) * LL + layer];

        int off = offs[node];
        int dg = deg[node];
        float a[8];
#pragma unroll
        for (int k = 0; k < 8; k++) a[k] = 0.f;
        int i = 0;
        // main: 8 edges per iter (4 per slot); 16B/lane gathers
        for (; i + 8 <= dg; i += 8) {
            int2 r0 = erec[off + i + slot];
            int2 r1 = erec[off + i + 2 + slot];
            int2 r2 = erec[off + i + 4 + slot];
            int2 r3 = erec[off + i + 6 + slot];
            us8 h0 = hph[(size_t)r0.x * 32 + c];
            us8 h1 = hph[(size_t)r1.x * 32 + c];
            us8 h2 = hph[(size_t)r2.x * 32 + c];
            us8 h3 = hph[(size_t)r3.x * 32 + c];
            us8 e0 = et[r0.y * 32 + c];
            us8 e1 = et[r1.y * 32 + c];
            us8 e2 = et[r2.y * 32 + c];
            us8 e3 = et[r3.y * 32 + c];
#pragma unroll
            for (int k = 0; k < 8; k++) {
                a[k] += fmaxf(bf2f(h0[k]) + bf2f(e0[k]), 0.f);
                a[k] += fmaxf(bf2f(h1[k]) + bf2f(e1[k]), 0.f);
                a[k] += fmaxf(bf2f(h2[k]) + bf2f(e2[k]), 0.f);
                a[k] += fmaxf(bf2f(h3[k]) + bf2f(e3[k]), 0.f);
            }
        }
        // remainder (<=7), 2 edges per iter, predicated
        for (; i < dg; i += 2) {
            int j = i + slot;
            bool valid = j < dg;
            int e = off + (valid ? j : 0);
            int2 r = erec[e];
            us8 h = hph[(size_t)r.x * 32 + c];
            us8 ev = et[r.y * 32 + c];
            if (valid) {
#pragma unroll
                for (int k = 0; k < 8; k++) a[k] += fmaxf(bf2f(h[k]) + bf2f(ev[k]), 0.f);
            }
        }
        // reduce across the 2 slots
#pragma unroll
        for (int k = 0; k < 8; k++) a[k] += __shfl_xor(a[k], 32, 64);

        // self (exact hi+lo): u = (1+eps)*h' + agg; split hi/lo
        us8 sh = hph[(size_t)node * 32 + c];
        us8 sl = hpl[(size_t)node * 32 + c];
        us8 uh, ul;
#pragma unroll
        for (int k = 0; k < 8; k++) {
            float u = ep * (bf2f(sh[k]) + bf2f(sl[k])) + a[k];
            unsigned short h = f2bf(u);
            uh[k] = h;
            ul[k] = f2bf(u - bf2f(h));
        }
        // u row = 64 us8: [t0hi 16][t1hi 16][t0lo 16][t1lo 16]; slot0 -> hi, slot1 -> lo
        int unit = slot * 32 + c;
        uS[row * 64 + (unit ^ (row & 7))] = slot ? ul : uh;
    }
    __syncthreads();

    // ---- Phase B: GEMM (16 rows x 256 cols, 16 wave-tiles) ----
    int tw = w >> 3, nt = w & 7;  // tower, col-tile (16 cols)
    int quad = lane >> 4, m = lane & 15;
    const bf8_t* Wh8 = (const bf8_t*)(Wbh + (size_t)(tw * LL + layer) * DD * DD);
    const bf8_t* Wl8 = (const bf8_t*)(Wbl + (size_t)(tw * LL + layer) * DD * DD);
    const float* bias = ball + (size_t)(tw * LL + layer) * DD;
    const bf8_t* u8 = (const bf8_t*)uS;

    f4_t acc;
    acc[0] = 0.f; acc[1] = 0.f; acc[2] = 0.f; acc[3] = 0.f;
    int lrow = m;           // A-row = lane m (block has exactly 16 rows)
    int sw = lrow & 7;
#pragma unroll
    for (int kt = 0; kt < 4; kt++) {
        int x = kt * 4 + quad;
        bf8_t ah = u8[lrow * 64 + (tw * 16 + (x ^ sw))];
        bf8_t al = u8[lrow * 64 + (32 + tw * 16 + (x ^ sw))];
        bf8_t bh = Wh8[(nt * 16 + m) * 16 + x];
        bf8_t bl = Wl8[(nt * 16 + m) * 16 + x];
        acc = __builtin_amdgcn_mfma_f32_16x16x32_bf16(ah, bh, acc, 0, 0, 0);
        acc = __builtin_amdgcn_mfma_f32_16x16x32_bf16(al, bh, acc, 0, 0, 0);
        acc = __builtin_amdgcn_mfma_f32_16x16x32_bf16(ah, bl, acc, 0, 0, 0);
    }
    __syncthreads();  // uS dead; accS about to be written

    // Epilogue: D layout col = nt*16 + m, row = quad*4 + r. Stage into LDS + stats.
    {
        int col = nt * 16 + m;
        float bv = bias[col];
        int gc = tw * 128 + col;
        int cg = gc >> 5, kk = gc & 31;
        float s = 0.f, q = 0.f;
#pragma unroll
        for (int r = 0; r < 4; r++) {
            int lr2 = quad * 4 + r;
            float v = acc[r] + bv;
            accS[(lr2 * 8 + cg) * 33 + kk] = v;
            s += v; q += v * v;   // all rows valid: 1250*16 == NN
        }
        s += __shfl_xor(s, 16, 64); s += __shfl_xor(s, 32, 64);
        q += __shfl_xor(q, 16, 64); q += __shfl_xor(q, 32, 64);
        if (quad == 0) {
            sP[tw][0][col] = s;
            sP[tw][1][col] = q;
        }
    }
    __syncthreads();

    // vectorized hi/lo stores: t<512 -> yh, t>=512 -> yl; row = (t&511)>>5, unit = t&31
    {
        int t = tid & 511;
        int row = t >> 5, unit = t & 31;   // unit: us8 of the 512B y-row
        int grow = blockIdx.x * 16 + row;
        int cg = unit >> 2, kb = (unit & 3) * 8;
        const float* srcp = accS + (row * 8 + cg) * 33 + kb;
        us8 v8;
        if (tid < 512) {
#pragma unroll
            for (int k = 0; k < 8; k++) v8[k] = f2bf(srcp[k]);
            ((us8*)yh)[(size_t)grow * 32 + unit] = v8;
        } else {
#pragma unroll
            for (int k = 0; k < 8; k++) {
                float v = srcp[k];
                v8[k] = f2bf(v - bf2f(f2bf(v)));
            }
            ((us8*)yl)[(size_t)grow * 32 + unit] = v8;
        }
    }

    // stats: tid < 512: tid = tw*256 + sq*128 + ch; one atomicAdd/thread
    if (tid < 512) {
        int twi = tid >> 8, idx = tid & 255;
        int sq = idx >> 7, ch = idx & 127;
        atomicAdd(&statsL[twi * 256 + idx], sP[twi][sq][ch]);
    }
}

// ---------------- final epilogue: BN (raw stats) + cross (no relu) from hi+lo -> d_out ----------------

__global__ __launch_bounds__(256) void bn_final_kernel(
    const ushort4* __restrict__ yh, const ushort4* __restrict__ yl,
    float4* __restrict__ o1, float4* __restrict__ o2,
    const float* __restrict__ statsL,
    const float* __restrict__ gall, const float* __restrict__ btall,
    const float* __restrict__ crossp) {
    int idx = blockIdx.x * 256 + threadIdx.x;  // < NN*32 exactly
    int r = idx >> 5, c = idx & 31;
    float4 s1, t1, s2, t2;
    bn_coeffs(statsL, gall, btall, LL - 1, c, s1, t1, s2, t2);
    float c00 = crossp[0], c01 = crossp[1], c10 = crossp[2], c11 = crossp[3];
    float4 v1 = add4(bf2f4(yh[(size_t)r * 64 + c]), bf2f4(yl[(size_t)r * 64 + c]));
    float4 v2 = add4(bf2f4(yh[(size_t)r * 64 + 32 + c]), bf2f4(yl[(size_t)r * 64 + 32 + c]));
    float4 n1, n2;
    xform4(v1, v2, s1, t1, s2, t2, c00, c01, c10, c11, 0, n1, n2);
    o1[(size_t)r * 32 + c] = n1;
    o2[(size_t)r * 32 + c] = n2;
}

// ---------------- launcher ----------------

extern "C" void kernel_launch(void* const* d_in, const int* in_sizes, int n_in,
                              void* d_out, int out_size, void* d_ws, size_t ws_size,
                              hipStream_t stream) {
    const int* x = (const int*)d_in[0];
    const int* eidx = (const int*)d_in[1];
    const int* eattr = (const int*)d_in[2];
    const float* emb1 = (const float*)d_in[3];
    const float* emb2 = (const float*)d_in[4];
    const float* etab = (const float*)d_in[5];
    const float* epsv = (const float*)d_in[6];
    const float* Wall = (const float*)d_in[7];
    const float* ball = (const float*)d_in[8];
    const float* gall = (const float*)d_in[9];
    const float* btall = (const float*)d_in[10];
    const float* cross = (const float*)d_in[11];
    float* out = (float*)d_out;

    const size_t ND = (size_t)NN * DD;  // 2,560,000
    char* p = (char*)d_ws;
    unsigned short* yh = (unsigned short*)p;   p += (size_t)NN * 256 * 2;  // gemm-out bf16 hi plane
    unsigned short* yl = (unsigned short*)p;   p += (size_t)NN * 256 * 2;  // gemm-out bf16 lo plane
    unsigned short* hph = (unsigned short*)p;  p += (size_t)NN * 256 * 2;  // h' hi plane
    unsigned short* hpl = (unsigned short*)p;  p += (size_t)NN * 256 * 2;  // h' lo plane
    unsigned short* eh = (unsigned short*)p;   p += (size_t)NN * 256 * 2;  // embedding hi plane
    unsigned short* el = (unsigned short*)p;   p += (size_t)NN * 256 * 2;  // embedding lo plane
    unsigned short* Wbh = (unsigned short*)p;  p += (size_t)2 * LL * DD * DD * 2;
    unsigned short* Wbl = (unsigned short*)p;  p += (size_t)2 * LL * DD * DD * 2;
    unsigned short* etb2 = (unsigned short*)p; p += (size_t)2 * LL * EVV * DD * 2;
    int* deg = (int*)p;               p += (size_t)NN * 4;
    int* offs = (int*)p;              p += (size_t)NN * 4;
    int* pos = (int*)p;               p += (size_t)NN * 4;
    int2* erec = (int2*)p;            p += (size_t)EE * 8;
    float* stats = (float*)p;         p += (size_t)LL * 512 * 4;  // per-layer raw {sum,sq}

    const int* src = eidx;
    const int* dst = eidx + EE;

    hipMemsetAsync(deg, 0, (size_t)NN * 4, stream);
    prep_kernel<<<EMB_BLOCKS + CVT_BLOCKS + CNT_BLOCKS + 1, 256, 0, stream>>>(
        x, (const float4*)emb1, (const float4*)emb2,
        (ushort4*)eh, (ushort4*)el,
        (const float4*)Wall, (ushort4*)Wbh, (ushort4*)Wbl, dst, deg, stats,
        etab, etb2);
    scan_kernel<<<1, 1024, 0, stream>>>(deg, offs, pos);
    scatter_kernel<<<EE / 256, 256, 0, stream>>>(src, dst, eattr, pos, erec);

    for (int l = 0; l < LL; l++) {
        const unsigned short* hsrc_h = eh;
        const unsigned short* hsrc_l = el;
        if (l > 0) {
            xform_kernel<<<(NN * 32) / 256, 256, 0, stream>>>(
                (const ushort4*)yh, (const ushort4*)yl,
                (ushort4*)hph, (ushort4*)hpl,
                stats + (size_t)(l - 1) * 512, gall, btall,
                cross + (l - 1) * 4, l - 1);
            hsrc_h = hph;
            hsrc_l = hpl;
        }
        agg_gemm_kernel<<<FB, 1024, 0, stream>>>(
            (const us8*)hsrc_h, (const us8*)hsrc_l, (const us8*)etb2, l,
            offs, deg, erec, epsv, Wbh, Wbl, ball, yh, yl,
            stats + (size_t)l * 512);
    }
    bn_final_kernel<<<(NN * 32) / 256, 256, 0, stream>>>(
        (const ushort4*)yh, (const ushort4*)yl, (float4*)out, (float4*)(out + ND),
        stats + (size_t)(LL - 1) * 512, gall, btall, cross + (LL - 1) * 4);
}